// Round 3
// baseline (15109.283 us; speedup 1.0000x reference)
//
#include <hip/hip_runtime.h>

#define TT 512
#define II 8
#define HH 32

__device__ __forceinline__ float rcpf_(float x) { return __builtin_amdgcn_rcpf(x); }
__device__ __forceinline__ float sigf_(float z) { return rcpf_(1.f + __expf(-z)); }
__device__ __forceinline__ float tanhf_(float z) {
  float a = fabsf(z);
  float e = __expf(-2.f * a);            // in (0,1], no overflow
  float th = (1.f - e) * rcpf_(1.f + e);
  return copysignf(th, z);
}

// 128-thread blocks = 2 waves; each wave independently handles 4 batches
// (disjoint LDS regions). Lane wl owns gate rows rA=wl, rB=wl+64 of both
// layers; weights stationary in VGPRs (208/lane). h stored [unit][batch4]
// so one ds_read_b128 broadcast feeds 8 FMAs (2 rows x 4 batches).
// launch_bounds(128,2): 2 waves/EU -> 8 waves/CU, VGPR cap 256.
// Grid 1024 = 4 blocks/CU: full residency, no tail.
__global__ __launch_bounds__(128, 2) void lstm_fused(
    const float* __restrict__ X,
    const float* __restrict__ ln_g, const float* __restrict__ ln_b,
    const float* __restrict__ Wih0g, const float* __restrict__ Whh0g,
    const float* __restrict__ bih0, const float* __restrict__ bhh0,
    const float* __restrict__ Wih1g, const float* __restrict__ Whh1g,
    const float* __restrict__ bih1, const float* __restrict__ bhh1,
    const float* __restrict__ W1, const float* __restrict__ b1,
    const float* __restrict__ W2, const float* __restrict__ b2,
    float* __restrict__ out)
{
  // per-wave region: XB[2][4][8][4]=256, H1[32][4]=128, H2=128,
  // PA[128][4]=512, PB[128][4]=512  -> 1536 floats/wave
  __shared__ __align__(16) float lds[2 * 1536];

  const int tid = threadIdx.x;
  const int wv = tid >> 6;
  const int wl = tid & 63;
  float* S  = lds + wv * 1536;
  float* XB = S;            // [chunk&1][ts][i][b]
  float* H1 = S + 256;      // [u][b]
  float* H2 = S + 384;      // [u][b]
  float* PA = S + 512;      // [row][b]  (layer-0 preacts)
  float* PB = S + 1024;     // [row][b]  (layer-1 preacts)

  const int b0 = blockIdx.x * 8 + wv * 4;   // this wave's 4 batches
  const int rA = wl, rB = wl + 64;          // owned gate rows

  // ---- weights -> registers (208/lane), once ----
  float wiA0[II], wiB0[II], whA0[HH], whB0[HH];
  float wiA1[HH], wiB1[HH], whA1[HH], whB1[HH];
  {
    const float4* p = (const float4*)(Wih0g + rA * II);
    float4 v = p[0]; wiA0[0]=v.x; wiA0[1]=v.y; wiA0[2]=v.z; wiA0[3]=v.w;
    v = p[1]; wiA0[4]=v.x; wiA0[5]=v.y; wiA0[6]=v.z; wiA0[7]=v.w;
    p = (const float4*)(Wih0g + rB * II);
    v = p[0]; wiB0[0]=v.x; wiB0[1]=v.y; wiB0[2]=v.z; wiB0[3]=v.w;
    v = p[1]; wiB0[4]=v.x; wiB0[5]=v.y; wiB0[6]=v.z; wiB0[7]=v.w;
  }
  #pragma unroll
  for (int q = 0; q < HH / 4; ++q) {
    float4 v;
    v = ((const float4*)(Whh0g + rA * HH))[q];
    whA0[4*q]=v.x; whA0[4*q+1]=v.y; whA0[4*q+2]=v.z; whA0[4*q+3]=v.w;
    v = ((const float4*)(Whh0g + rB * HH))[q];
    whB0[4*q]=v.x; whB0[4*q+1]=v.y; whB0[4*q+2]=v.z; whB0[4*q+3]=v.w;
    v = ((const float4*)(Wih1g + rA * HH))[q];
    wiA1[4*q]=v.x; wiA1[4*q+1]=v.y; wiA1[4*q+2]=v.z; wiA1[4*q+3]=v.w;
    v = ((const float4*)(Wih1g + rB * HH))[q];
    wiB1[4*q]=v.x; wiB1[4*q+1]=v.y; wiB1[4*q+2]=v.z; wiB1[4*q+3]=v.w;
    v = ((const float4*)(Whh1g + rA * HH))[q];
    whA1[4*q]=v.x; whA1[4*q+1]=v.y; whA1[4*q+2]=v.z; whA1[4*q+3]=v.w;
    v = ((const float4*)(Whh1g + rB * HH))[q];
    whB1[4*q]=v.x; whB1[4*q+1]=v.y; whB1[4*q+2]=v.z; whB1[4*q+3]=v.w;
  }
  const float bA0 = bih0[rA] + bhh0[rA], bB0 = bih0[rB] + bhh0[rB];
  const float bA1 = bih1[rA] + bhh1[rA], bB1 = bih1[rB] + bhh1[rB];

  // init h state
  H1[wl] = 0.f; H1[64 + wl] = 0.f;
  H2[wl] = 0.f; H2[64 + wl] = 0.f;
  float c1a = 0.f, c1b = 0.f, c2a = 0.f, c2b = 0.f;

  // ---- x staging lane mapping: (batch, ts-in-chunk, i-pair) ----
  const int bs = wl >> 4, tss = (wl >> 2) & 3, ip = wl & 3;
  const float lg0 = ln_g[2 * ip], lg1 = ln_g[2 * ip + 1];
  const float lb0 = ln_b[2 * ip], lb1 = ln_b[2 * ip + 1];
  const float* xp = X + (size_t)(b0 + bs) * (TT * II) + tss * II + 2 * ip;
  const int xw = tss * 32 + 8 * ip + bs;   // word in XB half-buffer
  float2 xr = *(const float2*)xp;          // chunk 0 preloaded
  xp += 4 * II;

  for (int ch = 0; ch < TT / 4; ++ch) {
    const int cb = (ch & 1) * 128;

    // ---- LN over I=8 (2 elems/lane, reduce over ip via shfl) ----
    {
      float s = xr.x + xr.y;
      s += __shfl_xor(s, 1); s += __shfl_xor(s, 2);
      const float mu = s * 0.125f;
      const float dx = xr.x - mu, dy = xr.y - mu;
      float q = dx * dx + dy * dy;
      q += __shfl_xor(q, 1); q += __shfl_xor(q, 2);
      const float inv = __builtin_amdgcn_rsqf(fmaf(q, 0.125f, 1e-5f));
      XB[cb + xw]     = fmaf(dx * inv, lg0, lb0);
      XB[cb + xw + 4] = fmaf(dy * inv, lg1, lb1);
    }
    // prefetch next chunk (hidden behind 4 t-steps of compute)
    float2 xrn = xr;
    if (ch < TT / 4 - 1) { xrn = *(const float2*)xp; xp += 4 * II; }
    __syncthreads();  // S_A: xbuf + prev h writes visible

    for (int ts4 = 0; ts4 < 4; ++ts4) {
      // ---- layer 0 dot ----
      float aA[4], aB[4];
      aA[0]=bA0; aA[1]=bA0; aA[2]=bA0; aA[3]=bA0;
      aB[0]=bB0; aB[1]=bB0; aB[2]=bB0; aB[3]=bB0;
      const float* xb = &XB[cb + ts4 * 32];
      #pragma unroll
      for (int k = 0; k < II; ++k) {
        const float4 xv = *(const float4*)&xb[k * 4];
        aA[0] = fmaf(wiA0[k], xv.x, aA[0]); aA[1] = fmaf(wiA0[k], xv.y, aA[1]);
        aA[2] = fmaf(wiA0[k], xv.z, aA[2]); aA[3] = fmaf(wiA0[k], xv.w, aA[3]);
        aB[0] = fmaf(wiB0[k], xv.x, aB[0]); aB[1] = fmaf(wiB0[k], xv.y, aB[1]);
        aB[2] = fmaf(wiB0[k], xv.z, aB[2]); aB[3] = fmaf(wiB0[k], xv.w, aB[3]);
      }
      #pragma unroll
      for (int k = 0; k < HH; ++k) {
        const float4 hv = *(const float4*)&H1[k * 4];
        aA[0] = fmaf(whA0[k], hv.x, aA[0]); aA[1] = fmaf(whA0[k], hv.y, aA[1]);
        aA[2] = fmaf(whA0[k], hv.z, aA[2]); aA[3] = fmaf(whA0[k], hv.w, aA[3]);
        aB[0] = fmaf(whB0[k], hv.x, aB[0]); aB[1] = fmaf(whB0[k], hv.y, aB[1]);
        aB[2] = fmaf(whB0[k], hv.z, aB[2]); aB[3] = fmaf(whB0[k], hv.w, aB[3]);
      }
      *(float4*)&PA[rA * 4] = make_float4(aA[0], aA[1], aA[2], aA[3]);
      *(float4*)&PA[rB * 4] = make_float4(aB[0], aB[1], aB[2], aB[3]);
      __syncthreads();  // S_B

      // ---- layer 0 elementwise: lane handles (u=wl>>2,b=wl&3) and (+16,b) ----
      {
        const float pi1 = PA[wl],      pf1 = PA[128 + wl];
        const float pg1 = PA[256 + wl], po1 = PA[384 + wl];
        const float pi2 = PA[64 + wl],  pf2 = PA[192 + wl];
        const float pg2 = PA[320 + wl], po2 = PA[448 + wl];
        c1a = fmaf(sigf_(pf1), c1a, sigf_(pi1) * tanhf_(pg1));
        const float h1a = sigf_(po1) * tanhf_(c1a);
        c1b = fmaf(sigf_(pf2), c1b, sigf_(pi2) * tanhf_(pg2));
        const float h1b = sigf_(po2) * tanhf_(c1b);
        H1[wl] = h1a;
        H1[64 + wl] = h1b;
      }
      __syncthreads();  // S_C

      // ---- layer 1 dot ----
      aA[0]=bA1; aA[1]=bA1; aA[2]=bA1; aA[3]=bA1;
      aB[0]=bB1; aB[1]=bB1; aB[2]=bB1; aB[3]=bB1;
      #pragma unroll
      for (int k = 0; k < HH; ++k) {
        const float4 hv = *(const float4*)&H1[k * 4];
        aA[0] = fmaf(wiA1[k], hv.x, aA[0]); aA[1] = fmaf(wiA1[k], hv.y, aA[1]);
        aA[2] = fmaf(wiA1[k], hv.z, aA[2]); aA[3] = fmaf(wiA1[k], hv.w, aA[3]);
        aB[0] = fmaf(wiB1[k], hv.x, aB[0]); aB[1] = fmaf(wiB1[k], hv.y, aB[1]);
        aB[2] = fmaf(wiB1[k], hv.z, aB[2]); aB[3] = fmaf(wiB1[k], hv.w, aB[3]);
      }
      #pragma unroll
      for (int k = 0; k < HH; ++k) {
        const float4 hv = *(const float4*)&H2[k * 4];
        aA[0] = fmaf(whA1[k], hv.x, aA[0]); aA[1] = fmaf(whA1[k], hv.y, aA[1]);
        aA[2] = fmaf(whA1[k], hv.z, aA[2]); aA[3] = fmaf(whA1[k], hv.w, aA[3]);
        aB[0] = fmaf(whB1[k], hv.x, aB[0]); aB[1] = fmaf(whB1[k], hv.y, aB[1]);
        aB[2] = fmaf(whB1[k], hv.z, aB[2]); aB[3] = fmaf(whB1[k], hv.w, aB[3]);
      }
      *(float4*)&PB[rA * 4] = make_float4(aA[0], aA[1], aA[2], aA[3]);
      *(float4*)&PB[rB * 4] = make_float4(aB[0], aB[1], aB[2], aB[3]);
      __syncthreads();  // S_D

      // ---- layer 1 elementwise ----
      {
        const float pi1 = PB[wl],       pf1 = PB[128 + wl];
        const float pg1 = PB[256 + wl],  po1 = PB[384 + wl];
        const float pi2 = PB[64 + wl],   pf2 = PB[192 + wl];
        const float pg2 = PB[320 + wl],  po2 = PB[448 + wl];
        c2a = fmaf(sigf_(pf1), c2a, sigf_(pi1) * tanhf_(pg1));
        const float h2a = sigf_(po1) * tanhf_(c2a);
        c2b = fmaf(sigf_(pf2), c2b, sigf_(pi2) * tanhf_(pg2));
        const float h2b = sigf_(po2) * tanhf_(c2b);
        H2[wl] = h2a;
        H2[64 + wl] = h2b;
      }
      // next ts: S_A-equivalent ordering provided by S_B of next iteration?
      // No -- L0 of next ts reads H1 (stable since S_C) and writes PA whose
      // readers finished before S_C; H2 written here is next read in L1 after
      // S_B,S_C of next ts. Within-wave LDS is in-order; cross-wave regions
      // are disjoint. Chunk boundary has S_A.
    }
    xr = xrn;
  }
  __syncthreads();

  // ---- head: out[b] = tanh(W2 @ relu(W1 @ h2 + b1) + b2) ----
  {
    const int j = wl & 15;   // F1 = 16
    const int bh = wl >> 4;
    float a = b1[j];
    const float4* wp = (const float4*)(W1 + j * HH);
    #pragma unroll
    for (int q = 0; q < HH / 4; ++q) {
      const float4 wv = wp[q];
      a = fmaf(wv.x, H2[(4 * q + 0) * 4 + bh], a);
      a = fmaf(wv.y, H2[(4 * q + 1) * 4 + bh], a);
      a = fmaf(wv.z, H2[(4 * q + 2) * 4 + bh], a);
      a = fmaf(wv.w, H2[(4 * q + 3) * 4 + bh], a);
    }
    float r = fmaxf(a, 0.f) * W2[j];
    r += __shfl_xor(r, 1);
    r += __shfl_xor(r, 2);
    r += __shfl_xor(r, 4);
    r += __shfl_xor(r, 8);
    if (j == 0) out[b0 + bh] = tanhf_(r + b2[0]);
  }
}

extern "C" void kernel_launch(void* const* d_in, const int* in_sizes, int n_in,
                              void* d_out, int out_size, void* d_ws, size_t ws_size,
                              hipStream_t stream) {
  const float* X     = (const float*)d_in[0];
  const float* ln_g  = (const float*)d_in[1];
  const float* ln_b  = (const float*)d_in[2];
  const float* Wih0g = (const float*)d_in[3];
  const float* Whh0g = (const float*)d_in[4];
  const float* bih0  = (const float*)d_in[5];
  const float* bhh0  = (const float*)d_in[6];
  const float* Wih1g = (const float*)d_in[7];
  const float* Whh1g = (const float*)d_in[8];
  const float* bih1  = (const float*)d_in[9];
  const float* bhh1  = (const float*)d_in[10];
  const float* W1    = (const float*)d_in[11];
  const float* b1    = (const float*)d_in[12];
  const float* W2    = (const float*)d_in[13];
  const float* b2    = (const float*)d_in[14];
  float* out = (float*)d_out;

  const int Bn = in_sizes[0] / (TT * II);   // 8192
  dim3 grid(Bn / 8), block(128);
  hipLaunchKernelGGL(lstm_fused, grid, block, 0, stream,
                     X, ln_g, ln_b, Wih0g, Whh0g, bih0, bhh0,
                     Wih1g, Whh1g, bih1, bhh1, W1, b1, W2, b2, out);
}

// Round 4
// 2120.431 us; speedup vs baseline: 7.1256x; 7.1256x over previous
//
#include <hip/hip_runtime.h>

#define TT 512
#define II 8
#define HH 32

__device__ __forceinline__ float rcpf_(float x) { return __builtin_amdgcn_rcpf(x); }
__device__ __forceinline__ float sigf_(float z) { return rcpf_(1.f + __expf(-z)); }
__device__ __forceinline__ float tanhf_(float z) {
  float a = fabsf(z);
  float e = __expf(-2.f * a);            // in (0,1], no overflow
  float th = (1.f - e) * rcpf_(1.f + e);
  return copysignf(th, z);
}

// 128 threads = 2 waves; 4 batches/block. Lane tid owns gate row `tid` of BOTH
// layers: 8+32+32+32 = 104 weight floats/lane -> fits the 128-VGPR cap that
// __launch_bounds__(128,2) imposes (empirical: cap = 256/waves_per_EU; rounds
// 1/3 spilled at 208 floats). 2 waves/SIMD restores latency hiding.
// Software pipeline: iteration j computes PA(j+1)=b0+Wih0*x(j+1)+Whh0*H1(j)
// and PB(j)=b1+Wih1*H1(j)+Whh1*H2(j-1) in ONE fused k-loop (H1 read shared),
// then one barrier, then both layers' elementwise, then one barrier.
__global__ __launch_bounds__(128, 2) void lstm_fused(
    const float* __restrict__ X,
    const float* __restrict__ ln_g, const float* __restrict__ ln_b,
    const float* __restrict__ Wih0g, const float* __restrict__ Whh0g,
    const float* __restrict__ bih0, const float* __restrict__ bhh0,
    const float* __restrict__ Wih1g, const float* __restrict__ Whh1g,
    const float* __restrict__ bih1, const float* __restrict__ bhh1,
    const float* __restrict__ W1, const float* __restrict__ b1,
    const float* __restrict__ W2, const float* __restrict__ b2,
    float* __restrict__ out)
{
  __shared__ __align__(16) float XB[2][4][II][4];   // [half][ts][i][b] LN'd x
  __shared__ __align__(16) float H1[HH][4];         // [u][b]
  __shared__ __align__(16) float H2[HH][4];         // [u][b]
  __shared__ __align__(16) float PA[4 * HH][4];     // [row][b] L0 preacts
  __shared__ __align__(16) float PB[4 * HH][4];     // [row][b] L1 preacts

  const int tid = threadIdx.x;        // 0..127 == owned gate row
  const int b0 = blockIdx.x * 4;

  // ---- weights -> registers (104/lane), once ----
  float wi0[II], wh0[HH], wi1[HH], wh1[HH];
  {
    const float4* p = (const float4*)(Wih0g + tid * II);
    float4 v = p[0]; wi0[0]=v.x; wi0[1]=v.y; wi0[2]=v.z; wi0[3]=v.w;
    v = p[1];        wi0[4]=v.x; wi0[5]=v.y; wi0[6]=v.z; wi0[7]=v.w;
  }
  #pragma unroll
  for (int q = 0; q < HH / 4; ++q) {
    float4 v;
    v = ((const float4*)(Whh0g + tid * HH))[q];
    wh0[4*q]=v.x; wh0[4*q+1]=v.y; wh0[4*q+2]=v.z; wh0[4*q+3]=v.w;
    v = ((const float4*)(Wih1g + tid * HH))[q];
    wi1[4*q]=v.x; wi1[4*q+1]=v.y; wi1[4*q+2]=v.z; wi1[4*q+3]=v.w;
    v = ((const float4*)(Whh1g + tid * HH))[q];
    wh1[4*q]=v.x; wh1[4*q+1]=v.y; wh1[4*q+2]=v.z; wh1[4*q+3]=v.w;
  }
  const float b0r = bih0[tid] + bhh0[tid];
  const float b1r = bih1[tid] + bhh1[tid];

  // init states
  ((float*)H1)[tid] = 0.f;
  ((float*)H2)[tid] = 0.f;
  float c1 = 0.f, c2 = 0.f;

  // ---- x staging: one value per thread per 4-ts chunk ----
  const int xi = tid & 7, xts = (tid >> 3) & 3, xb = tid >> 5;
  const float lg = ln_g[xi], lb = ln_b[xi];
  const float* xp = X + (size_t)(b0 + xb) * (TT * II) + xts * II + xi;
  float v0 = xp[0];                 // chunk 0
  float xr = xp[4 * II];            // chunk 1 (prefetched)
  const float* xq = xp + 8 * II;    // next prefetch: chunk 2

  // stage chunk 0 with LN (reduce over the 8 i-lanes)
  {
    float s = v0;
    s += __shfl_xor(s, 1); s += __shfl_xor(s, 2); s += __shfl_xor(s, 4);
    const float mu = s * 0.125f;
    const float d = v0 - mu;
    float q2 = d * d;
    q2 += __shfl_xor(q2, 1); q2 += __shfl_xor(q2, 2); q2 += __shfl_xor(q2, 4);
    const float inv = __builtin_amdgcn_rsqf(fmaf(q2, 0.125f, 1e-5f));
    XB[0][xts][xi][xb] = fmaf(d * inv, lg, lb);
  }
  __syncthreads();

  // ---- t=0: PA(0) = b0 + Wih0 * x(0)  (h is zero) ----
  {
    float pa0 = b0r, pa1 = b0r, pa2 = b0r, pa3 = b0r;
    #pragma unroll
    for (int k = 0; k < II; ++k) {
      const float4 xv = ((const float4*)&XB[0][0][0][0])[k];
      pa0 = fmaf(wi0[k], xv.x, pa0); pa1 = fmaf(wi0[k], xv.y, pa1);
      pa2 = fmaf(wi0[k], xv.z, pa2); pa3 = fmaf(wi0[k], xv.w, pa3);
    }
    ((float4*)PA)[tid] = make_float4(pa0, pa1, pa2, pa3);
  }
  __syncthreads();
  {
    const float pi = ((const float*)PA)[tid];
    const float pf = ((const float*)PA)[128 + tid];
    const float pg = ((const float*)PA)[256 + tid];
    const float po = ((const float*)PA)[384 + tid];
    c1 = fmaf(sigf_(pf), c1, sigf_(pi) * tanhf_(pg));
    ((float*)H1)[tid] = sigf_(po) * tanhf_(c1);
  }
  __syncthreads();

  // ---- main pipelined loop: j = 0..510 ----
  for (int j = 0; j < TT - 1; ++j) {
    const int c = j >> 2;
    if ((j & 3) == 0 && c < (TT / 4 - 1)) {
      // stage chunk c+1 from prefetch reg; prefetch chunk c+2
      const float v = xr;
      float s = v;
      s += __shfl_xor(s, 1); s += __shfl_xor(s, 2); s += __shfl_xor(s, 4);
      const float mu = s * 0.125f;
      const float d = v - mu;
      float q2 = d * d;
      q2 += __shfl_xor(q2, 1); q2 += __shfl_xor(q2, 2); q2 += __shfl_xor(q2, 4);
      const float inv = __builtin_amdgcn_rsqf(fmaf(q2, 0.125f, 1e-5f));
      XB[(c + 1) & 1][xts][xi][xb] = fmaf(d * inv, lg, lb);
      if (c + 2 < TT / 4) { xr = *xq; xq += 4 * II; }
      // safe without extra barrier: this half was last read 2+ barriers ago,
      // and its first reader is 3 iterations (6 barriers) ahead.
    }

    // ---- fused dot: PA(j+1) and PB(j), sharing the H1(j) reads ----
    float pa0 = b0r, pa1 = b0r, pa2 = b0r, pa3 = b0r;
    float pb0 = b1r, pb1 = b1r, pb2 = b1r, pb3 = b1r;
    {
      const int t1 = j + 1;
      const float* xrow = &XB[(t1 >> 2) & 1][t1 & 3][0][0];
      #pragma unroll
      for (int k = 0; k < II; ++k) {
        const float4 xv = ((const float4*)xrow)[k];
        pa0 = fmaf(wi0[k], xv.x, pa0); pa1 = fmaf(wi0[k], xv.y, pa1);
        pa2 = fmaf(wi0[k], xv.z, pa2); pa3 = fmaf(wi0[k], xv.w, pa3);
      }
    }
    #pragma unroll
    for (int k = 0; k < HH; ++k) {
      const float4 hv = ((const float4*)H1)[k];
      pa0 = fmaf(wh0[k], hv.x, pa0); pa1 = fmaf(wh0[k], hv.y, pa1);
      pa2 = fmaf(wh0[k], hv.z, pa2); pa3 = fmaf(wh0[k], hv.w, pa3);
      pb0 = fmaf(wi1[k], hv.x, pb0); pb1 = fmaf(wi1[k], hv.y, pb1);
      pb2 = fmaf(wi1[k], hv.z, pb2); pb3 = fmaf(wi1[k], hv.w, pb3);
      const float4 gv = ((const float4*)H2)[k];
      pb0 = fmaf(wh1[k], gv.x, pb0); pb1 = fmaf(wh1[k], gv.y, pb1);
      pb2 = fmaf(wh1[k], gv.z, pb2); pb3 = fmaf(wh1[k], gv.w, pb3);
    }
    ((float4*)PA)[tid] = make_float4(pa0, pa1, pa2, pa3);
    ((float4*)PB)[tid] = make_float4(pb0, pb1, pb2, pb3);
    __syncthreads();  // B1

    // ---- elementwise, both layers; lane = (u=tid>>2, b=tid&3) ----
    {
      const float pi = ((const float*)PA)[tid];
      const float pf = ((const float*)PA)[128 + tid];
      const float pg = ((const float*)PA)[256 + tid];
      const float po = ((const float*)PA)[384 + tid];
      c1 = fmaf(sigf_(pf), c1, sigf_(pi) * tanhf_(pg));
      ((float*)H1)[tid] = sigf_(po) * tanhf_(c1);   // H1(j+1)
    }
    {
      const float pi = ((const float*)PB)[tid];
      const float pf = ((const float*)PB)[128 + tid];
      const float pg = ((const float*)PB)[256 + tid];
      const float po = ((const float*)PB)[384 + tid];
      c2 = fmaf(sigf_(pf), c2, sigf_(pi) * tanhf_(pg));
      ((float*)H2)[tid] = sigf_(po) * tanhf_(c2);   // H2(j)
    }
    __syncthreads();  // B2
  }

  // ---- epilogue: PB(511) = b1 + Wih1*H1(511) + Whh1*H2(510) ----
  {
    float pb0 = b1r, pb1 = b1r, pb2 = b1r, pb3 = b1r;
    #pragma unroll
    for (int k = 0; k < HH; ++k) {
      const float4 hv = ((const float4*)H1)[k];
      pb0 = fmaf(wi1[k], hv.x, pb0); pb1 = fmaf(wi1[k], hv.y, pb1);
      pb2 = fmaf(wi1[k], hv.z, pb2); pb3 = fmaf(wi1[k], hv.w, pb3);
      const float4 gv = ((const float4*)H2)[k];
      pb0 = fmaf(wh1[k], gv.x, pb0); pb1 = fmaf(wh1[k], gv.y, pb1);
      pb2 = fmaf(wh1[k], gv.z, pb2); pb3 = fmaf(wh1[k], gv.w, pb3);
    }
    ((float4*)PB)[tid] = make_float4(pb0, pb1, pb2, pb3);
  }
  __syncthreads();
  {
    const float pi = ((const float*)PB)[tid];
    const float pf = ((const float*)PB)[128 + tid];
    const float pg = ((const float*)PB)[256 + tid];
    const float po = ((const float*)PB)[384 + tid];
    c2 = fmaf(sigf_(pf), c2, sigf_(pi) * tanhf_(pg));
    ((float*)H2)[tid] = sigf_(po) * tanhf_(c2);     // H2(511)
  }
  __syncthreads();

  // ---- head: out[b] = tanh(W2 @ relu(W1 @ h2 + b1) + b2) ----
  if (tid < 64) {
    const int jj = tid & 15;   // F1 = 16
    const int bh = tid >> 4;
    float a = b1[jj];
    const float4* wp = (const float4*)(W1 + jj * HH);
    #pragma unroll
    for (int q = 0; q < HH / 4; ++q) {
      const float4 wv = wp[q];
      a = fmaf(wv.x, H2[4 * q + 0][bh], a);
      a = fmaf(wv.y, H2[4 * q + 1][bh], a);
      a = fmaf(wv.z, H2[4 * q + 2][bh], a);
      a = fmaf(wv.w, H2[4 * q + 3][bh], a);
    }
    float r = fmaxf(a, 0.f) * W2[jj];
    r += __shfl_xor(r, 1);
    r += __shfl_xor(r, 2);
    r += __shfl_xor(r, 4);
    r += __shfl_xor(r, 8);
    if (jj == 0) out[b0 + bh] = tanhf_(r + b2[0]);
  }
}

extern "C" void kernel_launch(void* const* d_in, const int* in_sizes, int n_in,
                              void* d_out, int out_size, void* d_ws, size_t ws_size,
                              hipStream_t stream) {
  const float* X     = (const float*)d_in[0];
  const float* ln_g  = (const float*)d_in[1];
  const float* ln_b  = (const float*)d_in[2];
  const float* Wih0g = (const float*)d_in[3];
  const float* Whh0g = (const float*)d_in[4];
  const float* bih0  = (const float*)d_in[5];
  const float* bhh0  = (const float*)d_in[6];
  const float* Wih1g = (const float*)d_in[7];
  const float* Whh1g = (const float*)d_in[8];
  const float* bih1  = (const float*)d_in[9];
  const float* bhh1  = (const float*)d_in[10];
  const float* W1    = (const float*)d_in[11];
  const float* b1    = (const float*)d_in[12];
  const float* W2    = (const float*)d_in[13];
  const float* b2    = (const float*)d_in[14];
  float* out = (float*)d_out;

  const int Bn = in_sizes[0] / (TT * II);   // 8192
  dim3 grid(Bn / 4), block(128);
  hipLaunchKernelGGL(lstm_fused, grid, block, 0, stream,
                     X, ln_g, ln_b, Wih0g, Whh0g, bih0, bhh0,
                     Wih1g, Whh1g, bih1, bhh1, W1, b1, W2, b2, out);
}

// Round 5
// 889.619 us; speedup vs baseline: 16.9840x; 2.3835x over previous
//
#include <hip/hip_runtime.h>
#include <hip/hip_bf16.h>

#define TT 512
#define HH 32

typedef __attribute__((ext_vector_type(8))) short short8;
typedef __attribute__((ext_vector_type(4))) float f32x4;

__device__ __forceinline__ float rcpf_(float x) { return __builtin_amdgcn_rcpf(x); }
__device__ __forceinline__ float sigf_(float z) { return rcpf_(1.f + __expf(-z)); }
__device__ __forceinline__ float tanhf_(float z) {
  float a = fabsf(z);
  float e = __expf(-2.f * a);
  return copysignf((1.f - e) * rcpf_(1.f + e), z);
}
__device__ __forceinline__ ushort bf16u_(float x) {
  __hip_bfloat16 b = __float2bfloat16(x);
  ushort u; __builtin_memcpy(&u, &b, 2); return u;
}
__device__ __forceinline__ float bf16f_(ushort u) {
  __hip_bfloat16 b; __builtin_memcpy(&b, &u, 2); return __bfloat162float(b);
}

// split 8 f32 into bf16 hi + bf16 lo fragments (j-order = k-order)
__device__ __forceinline__ void split8_(const float* w, short8* hi, short8* lo) {
  union { short8 v; ushort u[8]; } H, L;
  #pragma unroll
  for (int i = 0; i < 8; ++i) {
    ushort h = bf16u_(w[i]);
    H.u[i] = h;
    L.u[i] = bf16u_(w[i] - bf16f_(h));
  }
  *hi = H.v; *lo = L.v;
}

// elementwise (i,f,g,o) for 8 units/lane from MFMA D-layout accs, update c,
// emit h as packed bf16 hi/lo into [b][u]-ordered LDS (B-frag-readable).
__device__ __forceinline__ void ew_store_(const f32x4* acc, const float* bias,
                                          float* cst, ushort* dhi, ushort* dlo,
                                          int q, int col) {
  #pragma unroll
  for (int g8 = 0; g8 < 2; ++g8) {
    ushort hh[4], ll[4];
    #pragma unroll
    for (int r = 0; r < 4; ++r) {
      const float pi = acc[0 + g8][r] + bias[0 * 8 + g8 * 4 + r];
      const float pf = acc[2 + g8][r] + bias[1 * 8 + g8 * 4 + r];
      const float pg = acc[4 + g8][r] + bias[2 * 8 + g8 * 4 + r];
      const float po = acc[6 + g8][r] + bias[3 * 8 + g8 * 4 + r];
      const float c = fmaf(sigf_(pf), cst[g8 * 4 + r], sigf_(pi) * tanhf_(pg));
      cst[g8 * 4 + r] = c;
      const float h = sigf_(po) * tanhf_(c);
      const ushort hu = bf16u_(h);
      hh[r] = hu;
      ll[r] = bf16u_(h - bf16f_(hu));
    }
    const int off = col * 32 + g8 * 16 + 4 * q;  // ushort index in [16][32]
    uint2 wh, wl;
    wh.x = (uint)hh[0] | ((uint)hh[1] << 16);
    wh.y = (uint)hh[2] | ((uint)hh[3] << 16);
    wl.x = (uint)ll[0] | ((uint)ll[1] << 16);
    wl.y = (uint)ll[2] | ((uint)ll[3] << 16);
    *(uint2*)&dhi[off] = wh;
    *(uint2*)&dlo[off] = wl;
  }
}

// LayerNorm one timestep's 8 inputs (all in-lane) + bf16 split + stage to X LDS
__device__ __forceinline__ void stageX_(float4 va, float4 vb, int tloc, int col,
                                        ushort (*Xhi)[16][8], ushort (*Xlo)[16][8],
                                        const volatile float* LNC) {
  float v[8] = {va.x, va.y, va.z, va.w, vb.x, vb.y, vb.z, vb.w};
  float s = 0.f;
  #pragma unroll
  for (int i = 0; i < 8; ++i) s += v[i];
  const float mu = s * 0.125f;
  float d[8], q2 = 0.f;
  #pragma unroll
  for (int i = 0; i < 8; ++i) { d[i] = v[i] - mu; q2 += d[i] * d[i]; }
  const float inv = __builtin_amdgcn_rsqf(fmaf(q2, 0.125f, 1e-5f));
  union { short8 v8; ushort u[8]; } H, L;
  #pragma unroll
  for (int i = 0; i < 8; ++i) {
    const float xn = fmaf(d[i] * inv, LNC[i], LNC[8 + i]);
    const ushort h = bf16u_(xn);
    H.u[i] = h;
    L.u[i] = bf16u_(xn - bf16f_(h));
  }
  *(short8*)&Xhi[tloc][col][0] = H.v8;
  *(short8*)&Xlo[tloc][col][0] = L.v8;
}

#define MFMA(A, B, C) __builtin_amdgcn_mfma_f32_16x16x32_bf16((A), (B), (C), 0, 0, 0)

// 2 waves/block: wave0 = layer0 (PA(t+1)), wave1 = layer1 (PB(t)).
// 16 batches/block (N=16 MFMA tile). 8 m-tiles cover 128 gate rows.
// 3-term bf16 split (hi*hi + hi*lo + lo*hi) per chunk; K-chunks: [x pad32] +
// [h1] for L0, [h1] + [h2] for L1 -> 48 MFMA/wave/t. One barrier per t.
__global__ __launch_bounds__(128, 1) void lstm_mfma(
    const float* __restrict__ X,
    const float* __restrict__ ln_g, const float* __restrict__ ln_b,
    const float* __restrict__ Wih0g, const float* __restrict__ Whh0g,
    const float* __restrict__ bih0, const float* __restrict__ bhh0,
    const float* __restrict__ Wih1g, const float* __restrict__ Whh1g,
    const float* __restrict__ bih1, const float* __restrict__ bhh1,
    const float* __restrict__ W1, const float* __restrict__ b1,
    const float* __restrict__ W2, const float* __restrict__ b2,
    float* __restrict__ out)
{
  __shared__ __align__(16) ushort H1hi[2][16][32], H1lo[2][16][32];
  __shared__ __align__(16) ushort H2hi[2][16][32], H2lo[2][16][32];
  __shared__ __align__(16) ushort Xhi[8][16][8], Xlo[8][16][8];
  __shared__ __align__(16) float LNC[16];

  const int tid = threadIdx.x;
  const int wv = tid >> 6;
  const int lane = tid & 63;
  const int q = lane >> 4;     // k-group / row-reg group
  const int col = lane & 15;   // batch (B/D/C col) and A row (m)
  const int b0 = blockIdx.x * 16;

  if (tid < 8) { LNC[tid] = ln_g[tid]; LNC[8 + tid] = ln_b[tid]; }

  // ---- A-fragments (weights), once ----
  short8 aAh[8], aAl[8], aBh[8], aBl[8];
  #pragma unroll
  for (int mt = 0; mt < 8; ++mt) {
    const int row = mt * 16 + col;
    float w8[8];
    if (wv == 0) {
      if (q == 0) {  // chunk A = Wih0 (K=8, rest of K-32 zero)
        const float4 a = ((const float4*)(Wih0g + row * 8))[0];
        const float4 b = ((const float4*)(Wih0g + row * 8))[1];
        w8[0]=a.x; w8[1]=a.y; w8[2]=a.z; w8[3]=a.w;
        w8[4]=b.x; w8[5]=b.y; w8[6]=b.z; w8[7]=b.w;
      } else {
        #pragma unroll
        for (int i = 0; i < 8; ++i) w8[i] = 0.f;
      }
    } else {        // chunk A = Wih1 (K=32)
      const float4* P = (const float4*)(Wih1g + row * HH + 8 * q);
      const float4 a = P[0], b = P[1];
      w8[0]=a.x; w8[1]=a.y; w8[2]=a.z; w8[3]=a.w;
      w8[4]=b.x; w8[5]=b.y; w8[6]=b.z; w8[7]=b.w;
    }
    split8_(w8, &aAh[mt], &aAl[mt]);
    {
      const float4* P = (const float4*)((wv ? Whh1g : Whh0g) + row * HH + 8 * q);
      const float4 a = P[0], b = P[1];
      w8[0]=a.x; w8[1]=a.y; w8[2]=a.z; w8[3]=a.w;
      w8[4]=b.x; w8[5]=b.y; w8[6]=b.z; w8[7]=b.w;
    }
    split8_(w8, &aBh[mt], &aBl[mt]);
  }

  // ---- biases: value for gate row G*32 + g8*16 + 4q + r ----
  float biasf[32];
  {
    const float* bi = wv ? bih1 : bih0;
    const float* bh = wv ? bhh1 : bhh0;
    #pragma unroll
    for (int G = 0; G < 4; ++G)
      #pragma unroll
      for (int g8 = 0; g8 < 2; ++g8)
        #pragma unroll
        for (int r = 0; r < 4; ++r) {
          const int rr = G * 32 + g8 * 16 + 4 * q + r;
          biasf[G * 8 + g8 * 4 + r] = bi[rr] + bh[rr];
        }
  }

  float cst[8];
  #pragma unroll
  for (int i = 0; i < 8; ++i) cst[i] = 0.f;

  float4 xpre0, xpre1, xpre2, xpre3;
  const float* xgb = X + (size_t)(b0 + col) * (TT * 8);

  // ---- prologue ----
  if (wv == 0) {
    // stage chunk 0 (t=0..7): lane handles t=2q, 2q+1 (16 contiguous floats)
    {
      const float4* P = (const float4*)(xgb + (2 * q) * 8);
      const float4 a = P[0], b = P[1], c = P[2], d = P[3];
      stageX_(a, b, 2 * q, col, Xhi, Xlo, LNC);
      stageX_(c, d, 2 * q + 1, col, Xhi, Xlo, LNC);
    }
    // prefetch chunk 1 (t=8..15)
    {
      const float4* P = (const float4*)(xgb + (8 + 2 * q) * 8);
      xpre0 = P[0]; xpre1 = P[1]; xpre2 = P[2]; xpre3 = P[3];
    }
    // PA(0) = Wih0 * x(0)  (h=0): x-chunk only
    f32x4 acc[8];
    #pragma unroll
    for (int mt = 0; mt < 8; ++mt) { f32x4 z = {0.f, 0.f, 0.f, 0.f}; acc[mt] = z; }
    const short8 bAh = *(const short8*)&Xhi[0][col][0];
    const short8 bAl = *(const short8*)&Xlo[0][col][0];
    #pragma unroll
    for (int mt = 0; mt < 8; ++mt) {
      acc[mt] = MFMA(aAh[mt], bAh, acc[mt]);
      acc[mt] = MFMA(aAh[mt], bAl, acc[mt]);
      acc[mt] = MFMA(aAl[mt], bAh, acc[mt]);
    }
    ew_store_(acc, biasf, cst, &H1hi[0][0][0], &H1lo[0][0][0], q, col);  // h1(0)
  } else {
    // zero h2(-1) buffer H2[1]
    union { short8 v; ushort u[8]; } Z;
    #pragma unroll
    for (int i = 0; i < 8; ++i) Z.u[i] = 0;
    *(short8*)&H2hi[1][col][8 * q] = Z.v;
    *(short8*)&H2lo[1][col][8 * q] = Z.v;
  }
  __syncthreads();

  // ---- main loop: iter j computes PA(j+1) [wave0] and PB(j) [wave1] ----
  for (int j = 0; j < TT - 1; ++j) {
    const int p = j & 1;  // H1[p] = h1(j); H2[1-p] = h2(j-1); write H1[1-p], H2[p]

    if (wv == 0 && ((j + 1) & 7) == 0) {
      // stage chunk (j+1)/8 from prefetch regs, then prefetch next
      stageX_(xpre0, xpre1, 2 * q, col, Xhi, Xlo, LNC);
      stageX_(xpre2, xpre3, 2 * q + 1, col, Xhi, Xlo, LNC);
      const int cn = ((j + 1) >> 3) + 1;
      if (cn < TT / 8) {
        const float4* P = (const float4*)(xgb + (cn * 8 + 2 * q) * 8);
        xpre0 = P[0]; xpre1 = P[1]; xpre2 = P[2]; xpre3 = P[3];
      }
    }

    short8 bAh, bAl, bBh, bBl;
    if (wv == 0) {
      const int tl = (j + 1) & 7;
      bAh = *(const short8*)&Xhi[tl][col][0];      // x(j+1) (same addr all q; A zero for q>0)
      bAl = *(const short8*)&Xlo[tl][col][0];
      bBh = *(const short8*)&H1hi[p][col][8 * q];  // h1(j)
      bBl = *(const short8*)&H1lo[p][col][8 * q];
    } else {
      bAh = *(const short8*)&H1hi[p][col][8 * q];      // h1(j)
      bAl = *(const short8*)&H1lo[p][col][8 * q];
      bBh = *(const short8*)&H2hi[1 - p][col][8 * q];  // h2(j-1)
      bBl = *(const short8*)&H2lo[1 - p][col][8 * q];
    }

    f32x4 acc[8];
    #pragma unroll
    for (int mt = 0; mt < 8; ++mt) { f32x4 z = {0.f, 0.f, 0.f, 0.f}; acc[mt] = z; }
    #pragma unroll
    for (int mt = 0; mt < 8; ++mt) {
      acc[mt] = MFMA(aAh[mt], bAh, acc[mt]);
      acc[mt] = MFMA(aAh[mt], bAl, acc[mt]);
      acc[mt] = MFMA(aAl[mt], bAh, acc[mt]);
      acc[mt] = MFMA(aBh[mt], bBh, acc[mt]);
      acc[mt] = MFMA(aBh[mt], bBl, acc[mt]);
      acc[mt] = MFMA(aBl[mt], bBh, acc[mt]);
    }

    ushort* dhi = wv ? &H2hi[p][0][0] : &H1hi[1 - p][0][0];
    ushort* dlo = wv ? &H2lo[p][0][0] : &H1lo[1 - p][0][0];
    ew_store_(acc, biasf, cst, dhi, dlo, q, col);
    __syncthreads();
  }

  // ---- epilogue: PB(511) on wave1; h1(511) is in H1[1], h2(510) in H2[0] ----
  if (wv == 1) {
    f32x4 acc[8];
    #pragma unroll
    for (int mt = 0; mt < 8; ++mt) { f32x4 z = {0.f, 0.f, 0.f, 0.f}; acc[mt] = z; }
    const short8 bAh = *(const short8*)&H1hi[1][col][8 * q];
    const short8 bAl = *(const short8*)&H1lo[1][col][8 * q];
    const short8 bBh = *(const short8*)&H2hi[0][col][8 * q];
    const short8 bBl = *(const short8*)&H2lo[0][col][8 * q];
    #pragma unroll
    for (int mt = 0; mt < 8; ++mt) {
      acc[mt] = MFMA(aAh[mt], bAh, acc[mt]);
      acc[mt] = MFMA(aAh[mt], bAl, acc[mt]);
      acc[mt] = MFMA(aAl[mt], bAh, acc[mt]);
      acc[mt] = MFMA(aBh[mt], bBh, acc[mt]);
      acc[mt] = MFMA(aBh[mt], bBl, acc[mt]);
      acc[mt] = MFMA(aBl[mt], bBh, acc[mt]);
    }
    ew_store_(acc, biasf, cst, &H2hi[1][0][0], &H2lo[1][0][0], q, col);  // h2(511)
  }
  __syncthreads();

  // ---- head on wave1: out[b] = tanh(W2 @ relu(W1 @ h2 + b1) + b2) ----
  if (wv == 1) {
    const int f = lane & 15;   // F1 = 16
    const int bg = lane >> 4;  // batch group (4 batches each)
    float w1r[32];
    {
      const float4* wp = (const float4*)(W1 + f * HH);
      #pragma unroll
      for (int qq = 0; qq < 8; ++qq) {
        const float4 v = wp[qq];
        w1r[4*qq]=v.x; w1r[4*qq+1]=v.y; w1r[4*qq+2]=v.z; w1r[4*qq+3]=v.w;
      }
    }
    const float w2 = W2[f], bb1 = b1[f], bb2 = b2[0];
    #pragma unroll
    for (int s = 0; s < 4; ++s) {
      const int b = bg * 4 + s;
      float a = bb1;
      #pragma unroll
      for (int u = 0; u < HH; ++u) {
        const float h = bf16f_(H2hi[1][b][u]) + bf16f_(H2lo[1][b][u]);
        a = fmaf(w1r[u], h, a);
      }
      float r = fmaxf(a, 0.f) * w2;
      r += __shfl_xor(r, 1);
      r += __shfl_xor(r, 2);
      r += __shfl_xor(r, 4);
      r += __shfl_xor(r, 8);
      if (f == 0) out[b0 + b] = tanhf_(r + bb2);
    }
  }
}

extern "C" void kernel_launch(void* const* d_in, const int* in_sizes, int n_in,
                              void* d_out, int out_size, void* d_ws, size_t ws_size,
                              hipStream_t stream) {
  const float* X     = (const float*)d_in[0];
  const float* ln_g  = (const float*)d_in[1];
  const float* ln_b  = (const float*)d_in[2];
  const float* Wih0g = (const float*)d_in[3];
  const float* Whh0g = (const float*)d_in[4];
  const float* bih0  = (const float*)d_in[5];
  const float* bhh0  = (const float*)d_in[6];
  const float* Wih1g = (const float*)d_in[7];
  const float* Whh1g = (const float*)d_in[8];
  const float* bih1  = (const float*)d_in[9];
  const float* bhh1  = (const float*)d_in[10];
  const float* W1    = (const float*)d_in[11];
  const float* b1    = (const float*)d_in[12];
  const float* W2    = (const float*)d_in[13];
  const float* b2    = (const float*)d_in[14];
  float* out = (float*)d_out;

  const int Bn = in_sizes[0] / (TT * 8);   // 8192
  dim3 grid(Bn / 16), block(128);
  hipLaunchKernelGGL(lstm_mfma, grid, block, 0, stream,
                     X, ln_g, ln_b, Wih0g, Whh0g, bih0, bhh0,
                     Wih1g, Whh1g, bih1, bhh1, W1, b1, W2, b2, out);
}

// Round 7
// 831.620 us; speedup vs baseline: 18.1685x; 1.0697x over previous
//
#include <hip/hip_runtime.h>
#include <hip/hip_bf16.h>

#define TT 512
#define HH 32

typedef __attribute__((ext_vector_type(8))) short short8;
typedef __attribute__((ext_vector_type(4))) float f32x4;

__device__ __forceinline__ float rcpf_(float x) { return __builtin_amdgcn_rcpf(x); }
__device__ __forceinline__ float sigf_(float z) { return rcpf_(1.f + __expf(-z)); }
__device__ __forceinline__ float tanhf_(float z) {
  float a = fabsf(z);
  float e = __expf(-2.f * a);
  return copysignf((1.f - e) * rcpf_(1.f + e), z);
}
__device__ __forceinline__ float bf16f_(ushort u) {
  uint b = (uint)u << 16;
  return __uint_as_float(b);
}

// cheap round-to-nearest bf16: add half-ulp then truncate. Exact-residual split.
__device__ __forceinline__ void split8_(const float* w, short8* hi, short8* lo) {
  union { short8 v; ushort u[8]; } H, L;
  #pragma unroll
  for (int i = 0; i < 8; ++i) {
    const uint hb = __float_as_uint(w[i]) + 0x8000u;
    H.u[i] = (ushort)(hb >> 16);
    const float hif = __uint_as_float(hb & 0xffff0000u);
    const uint lb = __float_as_uint(w[i] - hif) + 0x8000u;
    L.u[i] = (ushort)(lb >> 16);
  }
  *hi = H.v; *lo = L.v;
}

// LN one timestep (8 inputs in-lane) + bf16 hi/lo split -> X LDS row
__device__ __forceinline__ void stageX_(float4 va, float4 vb, int tloc, int col,
                                        ushort (*Xhi)[16][8], ushort (*Xlo)[16][8],
                                        const float* LNC) {
  float v[8] = {va.x, va.y, va.z, va.w, vb.x, vb.y, vb.z, vb.w};
  float s = 0.f;
  #pragma unroll
  for (int i = 0; i < 8; ++i) s += v[i];
  const float mu = s * 0.125f;
  float d[8], q2 = 0.f;
  #pragma unroll
  for (int i = 0; i < 8; ++i) { d[i] = v[i] - mu; q2 += d[i] * d[i]; }
  const float inv = __builtin_amdgcn_rsqf(fmaf(q2, 0.125f, 1e-5f));
  float xn[8];
  #pragma unroll
  for (int i = 0; i < 8; ++i) xn[i] = fmaf(d[i] * inv, LNC[i], LNC[8 + i]);
  short8 h8, l8;
  split8_(xn, &h8, &l8);
  *(short8*)&Xhi[tloc][col][0] = h8;
  *(short8*)&Xlo[tloc][col][0] = l8;
}

// elementwise for 4 units (D rows 4q+r), update c, store packed bf16 hi/lo (8B each)
__device__ __forceinline__ void ew4_(const f32x4* acc, const float* bias,
                                     float* cst, ushort* dhi, ushort* dlo) {
  uint hp[2], lp[2];
  #pragma unroll
  for (int pr = 0; pr < 2; ++pr) {
    uint h16[2], l16[2];
    #pragma unroll
    for (int s = 0; s < 2; ++s) {
      const int r = pr * 2 + s;
      const float pi = acc[0][r] + bias[r];
      const float pf = acc[1][r] + bias[4 + r];
      const float pg = acc[2][r] + bias[8 + r];
      const float po = acc[3][r] + bias[12 + r];
      const float c = fmaf(sigf_(pf), cst[r], sigf_(pi) * tanhf_(pg));
      cst[r] = c;
      const float h = sigf_(po) * tanhf_(c);
      const uint hb = __float_as_uint(h) + 0x8000u;
      const float hif = __uint_as_float(hb & 0xffff0000u);
      const uint lb = __float_as_uint(h - hif) + 0x8000u;
      h16[s] = hb >> 16;
      l16[s] = lb >> 16;
    }
    hp[pr] = h16[0] | (h16[1] << 16);
    lp[pr] = l16[0] | (l16[1] << 16);
  }
  *(uint2*)dhi = make_uint2(hp[0], hp[1]);
  *(uint2*)dlo = make_uint2(lp[0], lp[1]);
}

#define MFMA(A, B, C) __builtin_amdgcn_mfma_f32_16x16x32_bf16((A), (B), (C), 0, 0, 0)

// 256 threads = 4 waves; 16 batches/block. waves 0,1 = layer0, waves 2,3 = layer1.
// Wave w01 (=wv&1) owns m-tiles {2G+w01}: gate G rows 32G+16*w01+4q+r -> all 4
// gates of units 16*w01+4q+r live in one wave (in-register elementwise).
// Pipeline: iter j computes PA(j+1) (L0 waves) and PB(j) (L1 waves); 1 barrier/t.
// H rows padded 64B->80B: b128 start block 4*((20col+4q)/4 %32) spreads lanes
// 0-15 over all 8 bank-blocks (2-way max, free) -- round5 had 8-way.
// X is DOUBLE-BUFFERED by chunk parity (round-6 bug: single buffer clobbered
// slot 7 mid-consumption when staging moved to j%8==6). Chunk c in buf c&1;
// stage chunk c+1 at j=8c+6 (prev occupant chunk c-1 last read at j=8c-2; first
// reader of c+1 at j=8c+7, after the j=8c+6 barrier).
__global__ __launch_bounds__(256, 1) void lstm_mfma(
    const float* __restrict__ X,
    const float* __restrict__ ln_g, const float* __restrict__ ln_b,
    const float* __restrict__ Wih0g, const float* __restrict__ Whh0g,
    const float* __restrict__ bih0, const float* __restrict__ bhh0,
    const float* __restrict__ Wih1g, const float* __restrict__ Whh1g,
    const float* __restrict__ bih1, const float* __restrict__ bhh1,
    const float* __restrict__ W1, const float* __restrict__ b1,
    const float* __restrict__ W2, const float* __restrict__ b2,
    float* __restrict__ out)
{
  __shared__ __align__(16) ushort H1hi[2][16][40], H1lo[2][16][40];
  __shared__ __align__(16) ushort H2hi[2][16][40], H2lo[2][16][40];
  __shared__ __align__(16) ushort Xhi[2][8][16][8], Xlo[2][8][16][8];
  __shared__ float LNC[16];

  const int tid = threadIdx.x;
  const int wv = tid >> 6;
  const int lane = tid & 63;
  const int q = lane >> 4;       // k-group / D row-group
  const int col = lane & 15;     // batch col (B/D) and A row (m)
  const int layer = wv >> 1;
  const int w01 = wv & 1;
  const int ubase = w01 * 16 + 4 * q;   // first owned unit
  const int b0 = blockIdx.x * 16;

  if (tid < 8) { LNC[tid] = ln_g[tid]; LNC[8 + tid] = ln_b[tid]; }

  // ---- A-fragments (weights), once ----
  short8 aAh[4], aAl[4], aBh[4], aBl[4];
  #pragma unroll
  for (int G = 0; G < 4; ++G) {
    const int row = G * 32 + w01 * 16 + col;
    float w8[8];
    if (layer == 0) {
      if (q == 0) {
        const float4 a = ((const float4*)(Wih0g + row * 8))[0];
        const float4 b = ((const float4*)(Wih0g + row * 8))[1];
        w8[0]=a.x; w8[1]=a.y; w8[2]=a.z; w8[3]=a.w;
        w8[4]=b.x; w8[5]=b.y; w8[6]=b.z; w8[7]=b.w;
      } else {
        #pragma unroll
        for (int i = 0; i < 8; ++i) w8[i] = 0.f;
      }
    } else {
      const float4* P = (const float4*)(Wih1g + row * HH + 8 * q);
      const float4 a = P[0], b = P[1];
      w8[0]=a.x; w8[1]=a.y; w8[2]=a.z; w8[3]=a.w;
      w8[4]=b.x; w8[5]=b.y; w8[6]=b.z; w8[7]=b.w;
    }
    split8_(w8, &aAh[G], &aAl[G]);
    {
      const float4* P = (const float4*)((layer ? Whh1g : Whh0g) + row * HH + 8 * q);
      const float4 a = P[0], b = P[1];
      w8[0]=a.x; w8[1]=a.y; w8[2]=a.z; w8[3]=a.w;
      w8[4]=b.x; w8[5]=b.y; w8[6]=b.z; w8[7]=b.w;
    }
    split8_(w8, &aBh[G], &aBl[G]);
  }

  // ---- biases: biasf[G*4+r] = b[32G + 16*w01 + 4q + r] ----
  float biasf[16];
  {
    const float* bi = layer ? bih1 : bih0;
    const float* bh = layer ? bhh1 : bhh0;
    #pragma unroll
    for (int G = 0; G < 4; ++G)
      #pragma unroll
      for (int r = 0; r < 4; ++r) {
        const int rr = G * 32 + w01 * 16 + 4 * q + r;
        biasf[G * 4 + r] = bi[rr] + bh[rr];
      }
  }

  float cst[4] = {0.f, 0.f, 0.f, 0.f};

  float4 xpre0, xpre1, xpre2, xpre3;
  const float* xgb = X + (size_t)(b0 + col) * (TT * 8);

  // ---- prologue: stage chunk 0 -> buf 0, prefetch chunk 1 (wave 0) ----
  if (wv == 0) {
    const float4* P = (const float4*)(xgb + (2 * q) * 8);
    const float4 a = P[0], b = P[1], c = P[2], d = P[3];
    stageX_(a, b, 2 * q, col, Xhi[0], Xlo[0], LNC);
    stageX_(c, d, 2 * q + 1, col, Xhi[0], Xlo[0], LNC);
    const float4* Q = (const float4*)(xgb + (8 + 2 * q) * 8);
    xpre0 = Q[0]; xpre1 = Q[1]; xpre2 = Q[2]; xpre3 = Q[3];
  }
  if (layer == 1) {
    // zero h2(-1) = H2[1] slice
    *(uint2*)&H2hi[1][col][ubase] = make_uint2(0, 0);
    *(uint2*)&H2lo[1][col][ubase] = make_uint2(0, 0);
  }
  __syncthreads();

  // ---- t=0 for L0 waves: PA(0) = b0 + Wih0*x(0) ----
  if (layer == 0) {
    f32x4 acc[4];
    #pragma unroll
    for (int G = 0; G < 4; ++G) { f32x4 z = {0.f,0.f,0.f,0.f}; acc[G] = z; }
    const short8 bAh = *(const short8*)&Xhi[0][0][col][0];
    const short8 bAl = *(const short8*)&Xlo[0][0][col][0];
    #pragma unroll
    for (int G = 0; G < 4; ++G) {
      acc[G] = MFMA(aAh[G], bAh, acc[G]);
      acc[G] = MFMA(aAh[G], bAl, acc[G]);
      acc[G] = MFMA(aAl[G], bAh, acc[G]);
    }
    ew4_(acc, biasf, cst, &H1hi[0][col][ubase], &H1lo[0][col][ubase]);  // h1(0)
  }
  __syncthreads();

  // ---- main loop: iter j computes PA(j+1) [L0] and PB(j) [L1] ----
  for (int j = 0; j < TT - 1; ++j) {
    const int p = j & 1;  // H1[p]=h1(j), H2[1-p]=h2(j-1); write H1[1-p], H2[p]

    if (wv == 0 && (j & 7) == 6) {
      // stage chunk cn=(j+2)/8 into buf cn&1 (first consumed NEXT iter,
      // after this iter's barrier); prefetch chunk cn+1
      const int cn = (j + 2) >> 3;
      stageX_(xpre0, xpre1, 2 * q, col, Xhi[cn & 1], Xlo[cn & 1], LNC);
      stageX_(xpre2, xpre3, 2 * q + 1, col, Xhi[cn & 1], Xlo[cn & 1], LNC);
      if (cn + 1 < TT / 8) {
        const float4* P = (const float4*)(xgb + ((cn + 1) * 8 + 2 * q) * 8);
        xpre0 = P[0]; xpre1 = P[1]; xpre2 = P[2]; xpre3 = P[3];
      }
    }

    short8 bAh, bAl, bBh, bBl;
    if (layer == 0) {
      const int t1 = j + 1;
      const int xbuf = (t1 >> 3) & 1;
      const int tl = t1 & 7;
      bAh = *(const short8*)&Xhi[xbuf][tl][col][0];
      bAl = *(const short8*)&Xlo[xbuf][tl][col][0];
      bBh = *(const short8*)&H1hi[p][col][8 * q];
      bBl = *(const short8*)&H1lo[p][col][8 * q];
    } else {
      bAh = *(const short8*)&H1hi[p][col][8 * q];
      bAl = *(const short8*)&H1lo[p][col][8 * q];
      bBh = *(const short8*)&H2hi[1 - p][col][8 * q];
      bBl = *(const short8*)&H2lo[1 - p][col][8 * q];
    }

    f32x4 acc[4];
    #pragma unroll
    for (int G = 0; G < 4; ++G) { f32x4 z = {0.f,0.f,0.f,0.f}; acc[G] = z; }
    #pragma unroll
    for (int G = 0; G < 4; ++G) {
      acc[G] = MFMA(aAh[G], bAh, acc[G]);
      acc[G] = MFMA(aAh[G], bAl, acc[G]);
      acc[G] = MFMA(aAl[G], bAh, acc[G]);
      acc[G] = MFMA(aBh[G], bBh, acc[G]);
      acc[G] = MFMA(aBh[G], bBl, acc[G]);
      acc[G] = MFMA(aBl[G], bBh, acc[G]);
    }

    ushort* dhi = layer ? &H2hi[p][col][ubase] : &H1hi[1 - p][col][ubase];
    ushort* dlo = layer ? &H2lo[p][col][ubase] : &H1lo[1 - p][col][ubase];
    ew4_(acc, biasf, cst, dhi, dlo);
    __syncthreads();
  }

  // ---- epilogue: PB(511) on L1 waves; h1(511)=H1[1], h2(510)=H2[0] ----
  if (layer == 1) {
    f32x4 acc[4];
    #pragma unroll
    for (int G = 0; G < 4; ++G) { f32x4 z = {0.f,0.f,0.f,0.f}; acc[G] = z; }
    const short8 bAh = *(const short8*)&H1hi[1][col][8 * q];
    const short8 bAl = *(const short8*)&H1lo[1][col][8 * q];
    const short8 bBh = *(const short8*)&H2hi[0][col][8 * q];
    const short8 bBl = *(const short8*)&H2lo[0][col][8 * q];
    #pragma unroll
    for (int G = 0; G < 4; ++G) {
      acc[G] = MFMA(aAh[G], bAh, acc[G]);
      acc[G] = MFMA(aAh[G], bAl, acc[G]);
      acc[G] = MFMA(aAl[G], bAh, acc[G]);
      acc[G] = MFMA(aBh[G], bBh, acc[G]);
      acc[G] = MFMA(aBh[G], bBl, acc[G]);
      acc[G] = MFMA(aBl[G], bBh, acc[G]);
    }
    ew4_(acc, biasf, cst, &H2hi[1][col][ubase], &H2lo[1][col][ubase]);  // h2(511)
  }
  __syncthreads();

  // ---- head on wave 0: out[b] = tanh(W2 @ relu(W1 @ h2 + b1) + b2) ----
  if (wv == 0) {
    const int f = lane & 15;   // F1 = 16
    const int bg = lane >> 4;  // 4 batches per lane-group
    float w1r[32];
    {
      const float4* wp = (const float4*)(W1 + f * HH);
      #pragma unroll
      for (int qq = 0; qq < 8; ++qq) {
        const float4 v = wp[qq];
        w1r[4*qq]=v.x; w1r[4*qq+1]=v.y; w1r[4*qq+2]=v.z; w1r[4*qq+3]=v.w;
      }
    }
    const float w2 = W2[f], bb1 = b1[f], bb2 = b2[0];
    #pragma unroll
    for (int s = 0; s < 4; ++s) {
      const int b = bg * 4 + s;
      float a = bb1;
      #pragma unroll
      for (int u = 0; u < HH; ++u) {
        const float h = bf16f_(H2hi[1][b][u]) + bf16f_(H2lo[1][b][u]);
        a = fmaf(w1r[u], h, a);
      }
      float r = fmaxf(a, 0.f) * w2;
      r += __shfl_xor(r, 1);
      r += __shfl_xor(r, 2);
      r += __shfl_xor(r, 4);
      r += __shfl_xor(r, 8);
      if (f == 0) out[b0 + b] = tanhf_(r + bb2);
    }
  }
}

extern "C" void kernel_launch(void* const* d_in, const int* in_sizes, int n_in,
                              void* d_out, int out_size, void* d_ws, size_t ws_size,
                              hipStream_t stream) {
  const float* X     = (const float*)d_in[0];
  const float* ln_g  = (const float*)d_in[1];
  const float* ln_b  = (const float*)d_in[2];
  const float* Wih0g = (const float*)d_in[3];
  const float* Whh0g = (const float*)d_in[4];
  const float* bih0  = (const float*)d_in[5];
  const float* bhh0  = (const float*)d_in[6];
  const float* Wih1g = (const float*)d_in[7];
  const float* Whh1g = (const float*)d_in[8];
  const float* bih1  = (const float*)d_in[9];
  const float* bhh1  = (const float*)d_in[10];
  const float* W1    = (const float*)d_in[11];
  const float* b1    = (const float*)d_in[12];
  const float* W2    = (const float*)d_in[13];
  const float* b2    = (const float*)d_in[14];
  float* out = (float*)d_out;

  const int Bn = in_sizes[0] / (TT * 8);   // 8192
  dim3 grid(Bn / 16), block(256);
  hipLaunchKernelGGL(lstm_mfma, grid, block, 0, stream,
                     X, ln_g, ln_b, Wih0g, Whh0g, bih0, bhh0,
                     Wih1g, Whh1g, bih1, bhh1, W1, b1, W2, b2, out);
}